// Round 13
// baseline (164.354 us; speedup 1.0000x reference)
//
#include <hip/hip_runtime.h>
#include <math.h>

#define NN 5000      // nodes
#define NNP 5008     // padded rows for G (mm reads r16 rows; tail garbage is finite & discarded)
#define NE 40000     // edges
#define UU 64        // hidden units
#define FE 16        // edge features
#define FEP 17       // +1 pseudo-feature for edge_bias
#define KD (FEP*UU)  // 1088
#define KH2 (KD/2)   // 544 (K-half per matmul wave)
#define NSTEPS 4
#define NT 16        // nodes per mm tile
#define NBM ((NN+NT-1)/NT) // 313 mm blocks
#define NBG (NN/8)   // 625 gather blocks (8 waves, 1 node/wave)
#define SLOT 40      // per-node edge bucket capacity (mean deg 8, P(>=40)~1e-15)
#define CH 8         // gather pipeline chunk
#define WBN (UU*KD)  // 69632
#define GTN (192*64) // 12288

typedef _Float16 half8 __attribute__((ext_vector_type(8)));
typedef float f32x4 __attribute__((ext_vector_type(4)));

__device__ __forceinline__ float sigm(float x){ return 1.f/(1.f + __expf(-x)); }
__device__ __forceinline__ int rfl(int x){ return __builtin_amdgcn_readfirstlane(x); }

// ---- build f16 weight tables + zero per-node degree counters ----
__global__ void build_k(const float* __restrict__ ek, const float* __restrict__ eb,
                        const float* __restrict__ gk, const float* __restrict__ rk,
                        _Float16* __restrict__ wb, _Float16* __restrict__ gkt,
                        _Float16* __restrict__ rkt, int* __restrict__ deg){
  int tid = blockIdx.x*blockDim.x + threadIdx.x;
  if (tid < NN) deg[tid] = 0;
  if (tid < WBN){
    int i = tid / KD, k = tid - i*KD;
    int f = k >> 6, j = k & 63;
    float v = (f < FE) ? ek[f*4096 + i*64 + j] : eb[i*64 + j];
    wb[tid] = (_Float16)v;
  } else if (tid < WBN + GTN){
    int r = tid - WBN; int n = r >> 6, k = r & 63;
    gkt[r] = (_Float16)gk[k*192 + n];
  } else if (tid < WBN + 2*GTN){
    int r = tid - WBN - GTN; int n = r >> 6, k = r & 63;
    rkt[r] = (_Float16)rk[k*192 + n];
  }
}

// ---- bucket edges by src (atomic slot alloc; order canonicalized in prep_k) ----
__global__ void bucket_k(const int* __restrict__ pair, int* __restrict__ deg,
                         int* __restrict__ eidb){
  int e = blockIdx.x*blockDim.x + threadIdx.x;
  if (e < NE){
    int v = pair[2*e];
    int pos = atomicAdd(&deg[v], 1);
    if (pos < SLOT) eidb[v*SLOT + pos] = e;
  }
}

// ---- canonical rank + pack node-major nbr list and ef rows ----
__global__ __launch_bounds__(512) void prep_k(const int* __restrict__ pair,
                       const float* __restrict__ ef,
                       const int* __restrict__ deg,
                       const int* __restrict__ eidb,
                       int* __restrict__ nbrP, float* __restrict__ efP){
  int w = threadIdx.x >> 6, lane = threadIdx.x & 63;
  int v = blockIdx.x * 8 + w;
  if (v >= NN) return;
  int dg = deg[v]; if (dg > SLOT) dg = SLOT;
  if (lane < dg){
    int e = eidb[v*SLOT + lane];
    int rank = 0;
    for (int j=0; j<dg; ++j){ int ej = eidb[v*SLOT + j]; rank += (ej < e); }
    nbrP[v*SLOT + rank] = pair[2*e + 1];
    const float4* er = (const float4*)(ef + (size_t)e*FE);
    float4* ew = (float4*)(efP + ((size_t)v*SLOT + rank)*FE);
    ew[0] = er[0]; ew[1] = er[1]; ew[2] = er[2]; ew[3] = er[3];
  }
}

// ---- gather: ZERO LDS, 1 node/wave, 625 blocks -> ~20 waves/CU residency ----
// G[v, f*64+j] = sum_edges ef[e,f]*h[nbr,j]  (f16 out, coalesced row writes)
__global__ __launch_bounds__(512) void gather_k(const float* __restrict__ h_in,
        const int* __restrict__ deg, const int* __restrict__ nbrP,
        const float* __restrict__ efP, _Float16* __restrict__ G){
  int w = threadIdx.x >> 6, lane = threadIdx.x & 63;
  int v = blockIdx.x * 8 + w;
  if (v >= NN) return;
  int dg = deg[v]; if (dg > SLOT) dg = SLOT; dg = rfl(dg);
  int nbr = (lane < dg) ? nbrP[(size_t)v*SLOT + lane] : 0;
  const float* ebase = efP + (size_t)v*SLOT*FE;
  float g[FEP];
  #pragma unroll
  for (int f=0;f<FEP;++f) g[f] = 0.f;
  for (int c0=0; c0<dg; c0+=CH){
    float hj[CH];
    #pragma unroll
    for (int q=0;q<CH;++q){ int i=c0+q;
      int nb = __shfl(nbr, i);
      hj[q] = (i<dg) ? h_in[(size_t)nb*64 + lane] : 0.f; }
    #pragma unroll
    for (int q=0;q<CH;++q){ int i=c0+q;
      if (i<dg){
        const float4* er = (const float4*)(ebase + (size_t)i*FE);
        float4 e0 = er[0], e1 = er[1], e2 = er[2], e3 = er[3];
        float hj_ = hj[q];
        g[ 0]=fmaf(e0.x,hj_,g[ 0]); g[ 1]=fmaf(e0.y,hj_,g[ 1]);
        g[ 2]=fmaf(e0.z,hj_,g[ 2]); g[ 3]=fmaf(e0.w,hj_,g[ 3]);
        g[ 4]=fmaf(e1.x,hj_,g[ 4]); g[ 5]=fmaf(e1.y,hj_,g[ 5]);
        g[ 6]=fmaf(e1.z,hj_,g[ 6]); g[ 7]=fmaf(e1.w,hj_,g[ 7]);
        g[ 8]=fmaf(e2.x,hj_,g[ 8]); g[ 9]=fmaf(e2.y,hj_,g[ 9]);
        g[10]=fmaf(e2.z,hj_,g[10]); g[11]=fmaf(e2.w,hj_,g[11]);
        g[12]=fmaf(e3.x,hj_,g[12]); g[13]=fmaf(e3.y,hj_,g[13]);
        g[14]=fmaf(e3.z,hj_,g[14]); g[15]=fmaf(e3.w,hj_,g[15]);
        g[16] += hj_;
      } }
  }
  _Float16* grow = G + (size_t)v*KD;
  #pragma unroll
  for (int f=0;f<FEP;++f) grow[f*64 + lane] = (_Float16)g[f];
}

// ---- mm: K-split agg matmul (A from global G) + GRU; 13 KB LDS, 313 blocks ----
__global__ __launch_bounds__(512) void mm_k(const float* __restrict__ h_in,
        float* __restrict__ h_out, const _Float16* __restrict__ G,
        const _Float16* __restrict__ wb, const _Float16* __restrict__ gkt,
        const _Float16* __restrict__ rkt, const float* __restrict__ gb){
  __shared__ float    aggP[2][16][68]; // 8704 B (f32 K-half partials)
  __shared__ _Float16 aggT[16*72];     // 2304 B
  __shared__ _Float16 hT[16*72];       // 2304 B

  int tid = threadIdx.x;
  int w = tid >> 6, lane = tid & 63;
  int r16 = lane & 15, kh = lane >> 4;
  int vb = blockIdx.x * NT;

  // stage own h tile (f16), zero-padded past NN
  for (int i=tid; i<NT*64; i+=512){
    int lv = i >> 6, j = i & 63; int v = vb + lv;
    hT[lv*72 + j] = (_Float16)((v < NN) ? h_in[(size_t)v*64 + j] : 0.f);
  }
  __syncthreads();

  // ---- agg matmul, K-split: wave w = cols (w&3)*16.., K-half (w>>2) ----
  {
    int cg = w & 3, khalf = w >> 2;
    int koff = khalf * KH2;
    f32x4 acc = {0.f,0.f,0.f,0.f};
    const _Float16* ap = G  + (size_t)(vb + r16)*KD + koff + kh*8;
    const _Float16* bp = wb + (size_t)(cg*16 + r16)*KD + koff + kh*8;
    #pragma unroll 4
    for (int k0=0; k0<KH2; k0+=32){
      half8 a = *(const half8*)(ap + k0);
      half8 b = *(const half8*)(bp + k0);
      acc = __builtin_amdgcn_mfma_f32_16x16x32_f16(a, b, acc, 0, 0, 0);
    }
    #pragma unroll
    for (int r=0;r<4;++r) aggP[khalf][kh*4+r][cg*16 + r16] = acc[r];
  }
  __syncthreads();

  // combine K-half partials -> f16 aggT
  for (int i=tid; i<NT*64; i+=512){
    int rw = i >> 6, cl = i & 63;
    aggT[rw*72 + cl] = (_Float16)(aggP[0][rw][cl] + aggP[1][rw][cl]);
  }
  __syncthreads();

  // ---- GRU via MFMA: waves 0-3, wave w owns units uw = w*16 + r16; 16 rows ----
  if (w < 4){
    int uw = w*16 + r16;
    const _Float16* az = aggT + r16*72 + kh*8;
    const _Float16* ah = hT   + r16*72 + kh*8;
    f32x4 mxz={0.f,0.f,0.f,0.f}, mxr=mxz, mxh=mxz, mhz=mxz, mhr=mxz, mhh=mxz;
    #pragma unroll
    for (int ks=0; ks<2; ++ks){
      half8 aa = *(const half8*)(az + ks*32);
      half8 hh = *(const half8*)(ah + ks*32);
      half8 bz = *(const half8*)(gkt + (size_t)(      uw)*64 + ks*32 + kh*8);
      half8 br = *(const half8*)(gkt + (size_t)( 64 + uw)*64 + ks*32 + kh*8);
      half8 bh = *(const half8*)(gkt + (size_t)(128 + uw)*64 + ks*32 + kh*8);
      half8 cz = *(const half8*)(rkt + (size_t)(      uw)*64 + ks*32 + kh*8);
      half8 cr = *(const half8*)(rkt + (size_t)( 64 + uw)*64 + ks*32 + kh*8);
      half8 ch = *(const half8*)(rkt + (size_t)(128 + uw)*64 + ks*32 + kh*8);
      mxz = __builtin_amdgcn_mfma_f32_16x16x32_f16(aa, bz, mxz, 0,0,0);
      mxr = __builtin_amdgcn_mfma_f32_16x16x32_f16(aa, br, mxr, 0,0,0);
      mxh = __builtin_amdgcn_mfma_f32_16x16x32_f16(aa, bh, mxh, 0,0,0);
      mhz = __builtin_amdgcn_mfma_f32_16x16x32_f16(hh, cz, mhz, 0,0,0);
      mhr = __builtin_amdgcn_mfma_f32_16x16x32_f16(hh, cr, mhr, 0,0,0);
      mhh = __builtin_amdgcn_mfma_f32_16x16x32_f16(hh, ch, mhh, 0,0,0);
    }
    float b0z = gb[uw],      b0r = gb[64+uw],  b0h = gb[128+uw];
    float b1z = gb[192+uw],  b1r = gb[256+uw], b1h = gb[320+uw];
    #pragma unroll
    for (int r=0;r<4;++r){
      int row = vb + kh*4 + r;
      if (row < NN){
        float z  = sigm(mxz[r] + b0z + mhz[r] + b1z);
        float rr = sigm(mxr[r] + b0r + mhr[r] + b1r);
        float hc = tanhf(mxh[r] + b0h + rr*(mhh[r] + b1h));
        float hold = h_in[(size_t)row*64 + uw];
        h_out[(size_t)row*64 + uw] = z*hold + (1.f - z)*hc;
      }
    }
  }
}

extern "C" void kernel_launch(void* const* d_in, const int* in_sizes, int n_in,
                              void* d_out, int out_size, void* d_ws, size_t ws_size,
                              hipStream_t stream){
  const float* nodef = (const float*)d_in[0];
  const float* edgef = (const float*)d_in[1];
  const int*   pair  = (const int*)  d_in[2];
  const float* ek    = (const float*)d_in[3];
  const float* ebias = (const float*)d_in[4];
  const float* gk    = (const float*)d_in[5];
  const float* rk    = (const float*)d_in[6];
  const float* gb    = (const float*)d_in[7];

  char* ws = (char*)d_ws;
  size_t o = 0;
  auto carve = [&](size_t bytes)->char*{
    char* p = ws + o; o = (o + bytes + 255) & ~255ULL; return p; };
  int*      deg  = (int*)     carve(NN*sizeof(int));
  int*      eidb = (int*)     carve((size_t)NN*SLOT*sizeof(int));
  int*      nbrP = (int*)     carve((size_t)NN*SLOT*sizeof(int));
  float*    efP  = (float*)   carve((size_t)NN*SLOT*FE*sizeof(float));
  _Float16* G    = (_Float16*)carve((size_t)NNP*KD*sizeof(_Float16));
  _Float16* wb   = (_Float16*)carve((size_t)WBN*sizeof(_Float16));
  _Float16* gkt  = (_Float16*)carve((size_t)GTN*sizeof(_Float16));
  _Float16* rkt  = (_Float16*)carve((size_t)GTN*sizeof(_Float16));
  float*    hA   = (float*)   carve((size_t)NN*UU*sizeof(float));
  float*    hB   = (float*)   carve((size_t)NN*UU*sizeof(float));

  build_k <<<(WBN+2*GTN+255)/256, 256, 0, stream>>>(ek, ebias, gk, rk, wb, gkt, rkt, deg);
  bucket_k<<<(NE+255)/256, 256, 0, stream>>>(pair, deg, eidb);
  prep_k  <<<(NN+7)/8, 512, 0, stream>>>(pair, edgef, deg, eidb, nbrP, efP);

  const float* hin = nodef;
  for (int s=0; s<NSTEPS; ++s){
    float* hout = (s == NSTEPS-1) ? (float*)d_out : ((s & 1) ? hB : hA);
    gather_k<<<NBG, 512, 0, stream>>>(hin, deg, nbrP, efP, G);
    mm_k    <<<NBM, 512, 0, stream>>>(hin, hout, G, wb, gkt, rkt, gb);
    hin = hout;
  }
}

// Round 14
// 132.504 us; speedup vs baseline: 1.2404x; 1.2404x over previous
//
#include <hip/hip_runtime.h>
#include <math.h>

#define NN 5000      // nodes
#define NE 40000     // edges
#define UU 64        // hidden units
#define FE 16        // edge features
#define FEP 17       // +1 pseudo-feature for edge_bias
#define KD (FEP*UU)  // 1088
#define LDK (KD+8)   // padded LDS row (halfs); stride 548 dw == 4 mod 32
#define NSTEPS 4
#define NT 8         // nodes per step-tile (5000 % 8 == 0)
#define NBS (NN/NT)  // 625 step blocks
#define SLOT 40      // per-node edge bucket capacity (mean deg 8, P(>=40)~1e-15)
#define CH 8         // gather pipeline chunk
#define WBN (UU*KD)  // 69632
#define GTN (192*64) // 12288
#define PBLK 64      // pack blocks
#define NPB 79       // nodes per pack block (64*79 = 5056 >= 5000)

typedef _Float16 half8 __attribute__((ext_vector_type(8)));
typedef float f32x4 __attribute__((ext_vector_type(4)));

__device__ __forceinline__ float sigm(float x){ return 1.f/(1.f + __expf(-x)); }
__device__ __forceinline__ int rfl(int x){ return __builtin_amdgcn_readfirstlane(x); }

// ---- ONE pre kernel: weights (grid-stride) + deterministic edge pack ----
// block b owns nodes [b*NPB, b*NPB+NPB): scans all pairs, buckets into LDS,
// rank-sorts by edge id (canonical), emits deg/nbrP/efP.
__global__ __launch_bounds__(1024) void pack_k(
        const int* __restrict__ pair, const float* __restrict__ edgef,
        const float* __restrict__ ek, const float* __restrict__ eb,
        const float* __restrict__ gk, const float* __restrict__ rk,
        _Float16* __restrict__ wb, _Float16* __restrict__ gkt,
        _Float16* __restrict__ rkt,
        int* __restrict__ deg, int* __restrict__ nbrP, float* __restrict__ efP){
  __shared__ int cnt[NPB];
  __shared__ int el[NPB*SLOT];         // 12640 B

  int t = threadIdx.x;
  // part A: build f16 weight tables (independent of part B)
  for (int gt = blockIdx.x*1024 + t; gt < WBN + 2*GTN; gt += PBLK*1024){
    if (gt < WBN){
      int i = gt / KD, k = gt - i*KD;
      int f = k >> 6, j = k & 63;
      float v = (f < FE) ? ek[f*4096 + i*64 + j] : eb[i*64 + j];
      wb[gt] = (_Float16)v;
    } else if (gt < WBN + GTN){
      int r = gt - WBN; int n = r >> 6, k = r & 63;
      gkt[r] = (_Float16)gk[k*192 + n];
    } else {
      int r = gt - WBN - GTN; int n = r >> 6, k = r & 63;
      rkt[r] = (_Float16)rk[k*192 + n];
    }
  }

  // part B: bucket this block's node range in LDS
  int lo = blockIdx.x * NPB;
  int hi = lo + NPB; if (hi > NN) hi = NN;
  for (int i=t; i<NPB; i+=1024) cnt[i] = 0;
  __syncthreads();
  for (int e=t; e<NE; e+=1024){
    int2 pr = *(const int2*)(pair + 2*e);
    if (pr.x >= lo && pr.x < hi){
      int p = atomicAdd(&cnt[pr.x - lo], 1);
      if (p < SLOT) el[(pr.x - lo)*SLOT + p] = e;
    }
  }
  __syncthreads();
  // canonical order (rank by unique edge id) + emit packed lists
  int w = t >> 6, lane = t & 63;       // 16 waves
  for (int n = w; n < hi - lo; n += 16){
    int dg = cnt[n]; if (dg > SLOT) dg = SLOT;
    int v = lo + n;
    if (lane == 0) deg[v] = dg;
    if (lane < dg){
      int e = el[n*SLOT + lane];
      int rank = 0;
      for (int j=0; j<dg; ++j) rank += (el[n*SLOT + j] < e);
      nbrP[(size_t)v*SLOT + rank] = pair[2*e + 1];
      const float4* er = (const float4*)(edgef + (size_t)e*FE);
      float4* ew = (float4*)(efP + ((size_t)v*SLOT + rank)*FE);
      ew[0] = er[0]; ew[1] = er[1]; ew[2] = er[2]; ew[3] = er[3];
    }
  }
}

// ---- fused step, templated h dtypes: f32/f16 in, f16/f32 out ----
// 8 waves: gather 1 node/wave -> waves 0-3: MFMA agg (A rows 0-7) -> MFMA GRU.
template<typename TIN, typename TOUT>
__global__ __launch_bounds__(512) void step_k(const TIN* __restrict__ h_in,
        TOUT* __restrict__ h_out,
        const int* __restrict__ deg, const int* __restrict__ nbrP,
        const float* __restrict__ efP,
        const _Float16* __restrict__ wb, const _Float16* __restrict__ gkt,
        const _Float16* __restrict__ rkt, const float* __restrict__ gb){
  __shared__ _Float16 Gs[NT*LDK];      // 17536 B
  __shared__ _Float16 aggT[NT*72];     // 1152 B
  __shared__ _Float16 hT[NT*72];       // 1152 B

  int tid = threadIdx.x;
  int w = tid >> 6, lane = tid & 63;
  int r16 = lane & 15, kh = lane >> 4;
  int vb = blockIdx.x * NT;
  int v  = vb + w;                     // this wave's node

  hT[w*72 + lane] = (_Float16)(float)h_in[(size_t)v*64 + lane];

  // ---- gather: wave w owns node v; nbr via one lane-parallel load + shfl ----
  {
    int dg = deg[v]; if (dg > SLOT) dg = SLOT; dg = rfl(dg);
    int nbr = (lane < dg) ? nbrP[(size_t)v*SLOT + lane] : 0;
    const float* ebase = efP + (size_t)v*SLOT*FE;
    float g[FEP];
    #pragma unroll
    for (int f=0;f<FEP;++f) g[f] = 0.f;
    for (int c0=0; c0<dg; c0+=CH){
      float hj[CH];
      #pragma unroll
      for (int q=0;q<CH;++q){ int i=c0+q;
        int nb = __shfl(nbr, i);
        hj[q] = (i<dg) ? (float)h_in[(size_t)nb*64 + lane] : 0.f; }
      #pragma unroll
      for (int q=0;q<CH;++q){ int i=c0+q;
        if (i<dg){
          const float4* er = (const float4*)(ebase + (size_t)i*FE);
          float4 e0 = er[0], e1 = er[1], e2 = er[2], e3 = er[3];
          float hj_ = hj[q];
          g[ 0]=fmaf(e0.x,hj_,g[ 0]); g[ 1]=fmaf(e0.y,hj_,g[ 1]);
          g[ 2]=fmaf(e0.z,hj_,g[ 2]); g[ 3]=fmaf(e0.w,hj_,g[ 3]);
          g[ 4]=fmaf(e1.x,hj_,g[ 4]); g[ 5]=fmaf(e1.y,hj_,g[ 5]);
          g[ 6]=fmaf(e1.z,hj_,g[ 6]); g[ 7]=fmaf(e1.w,hj_,g[ 7]);
          g[ 8]=fmaf(e2.x,hj_,g[ 8]); g[ 9]=fmaf(e2.y,hj_,g[ 9]);
          g[10]=fmaf(e2.z,hj_,g[10]); g[11]=fmaf(e2.w,hj_,g[11]);
          g[12]=fmaf(e3.x,hj_,g[12]); g[13]=fmaf(e3.y,hj_,g[13]);
          g[14]=fmaf(e3.z,hj_,g[14]); g[15]=fmaf(e3.w,hj_,g[15]);
          g[16] += hj_;
        } }
    }
    #pragma unroll
    for (int f=0;f<FEP;++f) Gs[w*LDK + f*64 + lane] = (_Float16)g[f];
  }
  __syncthreads();

  // ---- agg matmul: waves 0-3, wave w = cols w*16..w*16+15; A rows 0-7 ----
  if (w < 4){
    f32x4 acc = {0.f,0.f,0.f,0.f};
    const _Float16* ap = Gs + (r16 & 7)*LDK + kh*8;
    const _Float16* bp = wb + (size_t)(w*16 + r16)*KD + kh*8;
    #pragma unroll 4
    for (int k0=0; k0<KD; k0+=32){
      half8 a = *(const half8*)(ap + k0);
      half8 b = *(const half8*)(bp + k0);
      acc = __builtin_amdgcn_mfma_f32_16x16x32_f16(a, b, acc, 0, 0, 0);
    }
    if (kh < 2){           // C rows 0-7 live in kh 0,1 (row = kh*4+r)
      #pragma unroll
      for (int r=0;r<4;++r) aggT[(kh*4+r)*72 + w*16 + r16] = (_Float16)acc[r];
    }
  }
  __syncthreads();

  // ---- GRU via MFMA: waves 0-3, wave w owns units uw = w*16 + r16 ----
  if (w < 4){
    int uw = w*16 + r16;
    const _Float16* az = aggT + (r16 & 7)*72 + kh*8;
    const _Float16* ah = hT   + (r16 & 7)*72 + kh*8;
    f32x4 mxz={0.f,0.f,0.f,0.f}, mxr=mxz, mxh=mxz, mhz=mxz, mhr=mxz, mhh=mxz;
    #pragma unroll
    for (int ks=0; ks<2; ++ks){
      half8 aa = *(const half8*)(az + ks*32);
      half8 hh = *(const half8*)(ah + ks*32);
      half8 bz = *(const half8*)(gkt + (size_t)(      uw)*64 + ks*32 + kh*8);
      half8 br = *(const half8*)(gkt + (size_t)( 64 + uw)*64 + ks*32 + kh*8);
      half8 bh = *(const half8*)(gkt + (size_t)(128 + uw)*64 + ks*32 + kh*8);
      half8 cz = *(const half8*)(rkt + (size_t)(      uw)*64 + ks*32 + kh*8);
      half8 cr = *(const half8*)(rkt + (size_t)( 64 + uw)*64 + ks*32 + kh*8);
      half8 ch = *(const half8*)(rkt + (size_t)(128 + uw)*64 + ks*32 + kh*8);
      mxz = __builtin_amdgcn_mfma_f32_16x16x32_f16(aa, bz, mxz, 0,0,0);
      mxr = __builtin_amdgcn_mfma_f32_16x16x32_f16(aa, br, mxr, 0,0,0);
      mxh = __builtin_amdgcn_mfma_f32_16x16x32_f16(aa, bh, mxh, 0,0,0);
      mhz = __builtin_amdgcn_mfma_f32_16x16x32_f16(hh, cz, mhz, 0,0,0);
      mhr = __builtin_amdgcn_mfma_f32_16x16x32_f16(hh, cr, mhr, 0,0,0);
      mhh = __builtin_amdgcn_mfma_f32_16x16x32_f16(hh, ch, mhh, 0,0,0);
    }
    if (kh < 2){
      float b0z = gb[uw],      b0r = gb[64+uw],  b0h = gb[128+uw];
      float b1z = gb[192+uw],  b1r = gb[256+uw], b1h = gb[320+uw];
      #pragma unroll
      for (int r=0;r<4;++r){
        int row = vb + kh*4 + r;
        float z  = sigm(mxz[r] + b0z + mhz[r] + b1z);
        float rr = sigm(mxr[r] + b0r + mhr[r] + b1r);
        float hc = tanhf(mxh[r] + b0h + rr*(mhh[r] + b1h));
        float hold = (float)h_in[(size_t)row*64 + uw];
        h_out[(size_t)row*64 + uw] = (TOUT)(z*hold + (1.f - z)*hc);
      }
    }
  }
}

extern "C" void kernel_launch(void* const* d_in, const int* in_sizes, int n_in,
                              void* d_out, int out_size, void* d_ws, size_t ws_size,
                              hipStream_t stream){
  const float* nodef = (const float*)d_in[0];
  const float* edgef = (const float*)d_in[1];
  const int*   pair  = (const int*)  d_in[2];
  const float* ek    = (const float*)d_in[3];
  const float* ebias = (const float*)d_in[4];
  const float* gk    = (const float*)d_in[5];
  const float* rk    = (const float*)d_in[6];
  const float* gb    = (const float*)d_in[7];

  char* ws = (char*)d_ws;
  size_t o = 0;
  auto carve = [&](size_t bytes)->char*{
    char* p = ws + o; o = (o + bytes + 255) & ~255ULL; return p; };
  int*      deg  = (int*)     carve(NN*sizeof(int));
  int*      nbrP = (int*)     carve((size_t)NN*SLOT*sizeof(int));
  float*    efP  = (float*)   carve((size_t)NN*SLOT*FE*sizeof(float));
  _Float16* wb   = (_Float16*)carve((size_t)WBN*sizeof(_Float16));
  _Float16* gkt  = (_Float16*)carve((size_t)GTN*sizeof(_Float16));
  _Float16* rkt  = (_Float16*)carve((size_t)GTN*sizeof(_Float16));
  _Float16* h16A = (_Float16*)carve((size_t)NN*UU*sizeof(_Float16));
  _Float16* h16B = (_Float16*)carve((size_t)NN*UU*sizeof(_Float16));

  pack_k<<<PBLK, 1024, 0, stream>>>(pair, edgef, ek, ebias, gk, rk,
                                    wb, gkt, rkt, deg, nbrP, efP);

  // steps: f32 nodef -> f16 -> f16 -> f16 -> f32 d_out
  step_k<float, _Float16><<<NBS, 512, 0, stream>>>(nodef, h16A, deg, nbrP, efP,
                                                   wb, gkt, rkt, gb);
  step_k<_Float16, _Float16><<<NBS, 512, 0, stream>>>(h16A, h16B, deg, nbrP, efP,
                                                      wb, gkt, rkt, gb);
  step_k<_Float16, _Float16><<<NBS, 512, 0, stream>>>(h16B, h16A, deg, nbrP, efP,
                                                      wb, gkt, rkt, gb);
  step_k<_Float16, float><<<NBS, 512, 0, stream>>>(h16A, (float*)d_out, deg, nbrP, efP,
                                                   wb, gkt, rkt, gb);
}

// Round 15
// 114.878 us; speedup vs baseline: 1.4307x; 1.1534x over previous
//
#include <hip/hip_runtime.h>
#include <math.h>

#define NN 5000      // nodes
#define NE 40000     // edges
#define UU 64        // hidden units
#define FE 16        // edge features
#define FEP 17       // +1 pseudo-feature for edge_bias
#define KD (FEP*UU)  // 1088
#define LDK (KD+8)   // padded LDS row (halfs); stride 548 dw == 4 mod 32
#define NSTEPS 4
#define NT 8         // nodes per step-tile (5000 % 8 == 0)
#define NB (NN/NT)   // 625 blocks
#define SLOT 40      // per-node edge bucket capacity (mean deg 8, P(>=40)~1e-15)
#define CH 8         // gather pipeline chunk
#define WBN (UU*KD)  // 69632
#define GTN (192*64) // 12288

typedef _Float16 half8 __attribute__((ext_vector_type(8)));
typedef float f32x4 __attribute__((ext_vector_type(4)));

__device__ __forceinline__ float sigm(float x){ return 1.f/(1.f + __expf(-x)); }
__device__ __forceinline__ int rfl(int x){ return __builtin_amdgcn_readfirstlane(x); }

// ---- build f16 weight tables + zero per-node degree counters ----
__global__ void build_k(const float* __restrict__ ek, const float* __restrict__ eb,
                        const float* __restrict__ gk, const float* __restrict__ rk,
                        _Float16* __restrict__ wb, _Float16* __restrict__ gkt,
                        _Float16* __restrict__ rkt, int* __restrict__ deg){
  int tid = blockIdx.x*blockDim.x + threadIdx.x;
  if (tid < NN) deg[tid] = 0;
  if (tid < WBN){
    int i = tid / KD, k = tid - i*KD;
    int f = k >> 6, j = k & 63;
    float v = (f < FE) ? ek[f*4096 + i*64 + j] : eb[i*64 + j];
    wb[tid] = (_Float16)v;
  } else if (tid < WBN + GTN){
    int r = tid - WBN; int n = r >> 6, k = r & 63;
    gkt[r] = (_Float16)gk[k*192 + n];
  } else if (tid < WBN + 2*GTN){
    int r = tid - WBN - GTN; int n = r >> 6, k = r & 63;
    rkt[r] = (_Float16)rk[k*192 + n];
  }
}

// ---- bucket edges by src (atomic slot alloc; order canonicalized in prep_k) ----
__global__ void bucket_k(const int* __restrict__ pair, int* __restrict__ deg,
                         int* __restrict__ eidb){
  int e = blockIdx.x*blockDim.x + threadIdx.x;
  if (e < NE){
    int v = pair[2*e];
    int pos = atomicAdd(&deg[v], 1);
    if (pos < SLOT) eidb[v*SLOT + pos] = e;
  }
}

// ---- canonical order via lane-parallel rank (edge ids unique) + resolve nbr ----
__global__ __launch_bounds__(512) void prep_k(const int* __restrict__ pair,
                       const int* __restrict__ deg,
                       const int* __restrict__ eidb, int2* __restrict__ enb){
  int w = threadIdx.x >> 6, lane = threadIdx.x & 63;
  int v = blockIdx.x * 8 + w;
  if (v >= NN) return;
  int dg = deg[v]; if (dg > SLOT) dg = SLOT;
  if (lane < dg){
    int e = eidb[v*SLOT + lane];
    int rank = 0;
    for (int j=0; j<dg; ++j){ int ej = eidb[v*SLOT + j]; rank += (ej < e); }
    enb[v*SLOT + rank] = make_int2(e, pair[2*e + 1]);
  }
}

// ---- fused step, 8-node tile, 8 waves: gather (1 wave/node) -> MFMA agg -> MFMA GRU ----
__global__ __launch_bounds__(512) void step_k(const float* __restrict__ h_in,
        float* __restrict__ h_out, const float* __restrict__ ef,
        const int* __restrict__ deg, const int2* __restrict__ enb,
        const _Float16* __restrict__ wb, const _Float16* __restrict__ gkt,
        const _Float16* __restrict__ rkt, const float* __restrict__ gb){
  __shared__ _Float16 Gs[NT*LDK];      // 17536 B
  __shared__ _Float16 aggT[NT*72];     // 1152 B
  __shared__ _Float16 hT[NT*72];       // 1152 B

  int tid = threadIdx.x;
  int w = tid >> 6, lane = tid & 63;
  int r16 = lane & 15, kh = lane >> 4;
  int vb = blockIdx.x * NT;
  int v  = vb + w;                     // this wave's node

  hT[w*72 + lane] = (_Float16)h_in[(size_t)v*64 + lane];

  // ---- gather: wave w owns node v (17 features, lane = unit) ----
  {
    int dgv = rfl(deg[v]); if (dgv > SLOT) dgv = SLOT;
    const int2* lst = enb + v*SLOT;
    float g[FEP];
    #pragma unroll
    for (int f=0;f<FEP;++f) g[f] = 0.f;
    for (int c0=0; c0<dgv; c0+=CH){
      int ee[CH], nb[CH];
      #pragma unroll
      for (int q=0;q<CH;++q){ int i=c0+q;
        if (i<dgv){ int2 p = lst[i]; ee[q]=rfl(p.x); nb[q]=rfl(p.y); }
        else { ee[q]=0; nb[q]=0; } }
      float hj[CH];
      #pragma unroll
      for (int q=0;q<CH;++q){ int i=c0+q;
        hj[q] = (i<dgv) ? h_in[(size_t)nb[q]*64 + lane] : 0.f; }
      #pragma unroll
      for (int q=0;q<CH;++q){ int i=c0+q;
        if (i<dgv){
          const float4* er = (const float4*)(ef + (size_t)ee[q]*FE);
          float4 e0 = er[0], e1 = er[1], e2 = er[2], e3 = er[3];
          g[ 0]=fmaf(e0.x,hj[q],g[ 0]); g[ 1]=fmaf(e0.y,hj[q],g[ 1]);
          g[ 2]=fmaf(e0.z,hj[q],g[ 2]); g[ 3]=fmaf(e0.w,hj[q],g[ 3]);
          g[ 4]=fmaf(e1.x,hj[q],g[ 4]); g[ 5]=fmaf(e1.y,hj[q],g[ 5]);
          g[ 6]=fmaf(e1.z,hj[q],g[ 6]); g[ 7]=fmaf(e1.w,hj[q],g[ 7]);
          g[ 8]=fmaf(e2.x,hj[q],g[ 8]); g[ 9]=fmaf(e2.y,hj[q],g[ 9]);
          g[10]=fmaf(e2.z,hj[q],g[10]); g[11]=fmaf(e2.w,hj[q],g[11]);
          g[12]=fmaf(e3.x,hj[q],g[12]); g[13]=fmaf(e3.y,hj[q],g[13]);
          g[14]=fmaf(e3.z,hj[q],g[14]); g[15]=fmaf(e3.w,hj[q],g[15]);
          g[16] += hj[q];
        } }
    }
    #pragma unroll
    for (int f=0;f<FEP;++f) Gs[w*LDK + f*64 + lane] = (_Float16)g[f];
  }
  __syncthreads();

  // ---- agg matmul: waves 0-3, wave w = cols w*16..w*16+15; A rows 0-7 valid ----
  if (w < 4){
    f32x4 acc = {0.f,0.f,0.f,0.f};
    const _Float16* ap = Gs + (r16 & 7)*LDK + kh*8;
    const _Float16* bp = wb + (size_t)(w*16 + r16)*KD + kh*8;
    #pragma unroll 4
    for (int k0=0; k0<KD; k0+=32){
      half8 a = *(const half8*)(ap + k0);
      half8 b = *(const half8*)(bp + k0);
      acc = __builtin_amdgcn_mfma_f32_16x16x32_f16(a, b, acc, 0, 0, 0);
    }
    if (kh < 2){           // C rows 0-7 live in kh 0,1 (row = kh*4+r)
      #pragma unroll
      for (int r=0;r<4;++r) aggT[(kh*4+r)*72 + w*16 + r16] = (_Float16)acc[r];
    }
  }
  __syncthreads();

  // ---- GRU via MFMA: waves 0-3, wave w owns units uw = w*16 + r16 ----
  if (w < 4){
    int uw = w*16 + r16;
    const _Float16* az = aggT + (r16 & 7)*72 + kh*8;
    const _Float16* ah = hT   + (r16 & 7)*72 + kh*8;
    f32x4 mxz={0.f,0.f,0.f,0.f}, mxr=mxz, mxh=mxz, mhz=mxz, mhr=mxz, mhh=mxz;
    #pragma unroll
    for (int ks=0; ks<2; ++ks){
      half8 aa = *(const half8*)(az + ks*32);
      half8 hh = *(const half8*)(ah + ks*32);
      half8 bz = *(const half8*)(gkt + (size_t)(      uw)*64 + ks*32 + kh*8);
      half8 br = *(const half8*)(gkt + (size_t)( 64 + uw)*64 + ks*32 + kh*8);
      half8 bh = *(const half8*)(gkt + (size_t)(128 + uw)*64 + ks*32 + kh*8);
      half8 cz = *(const half8*)(rkt + (size_t)(      uw)*64 + ks*32 + kh*8);
      half8 cr = *(const half8*)(rkt + (size_t)( 64 + uw)*64 + ks*32 + kh*8);
      half8 ch = *(const half8*)(rkt + (size_t)(128 + uw)*64 + ks*32 + kh*8);
      mxz = __builtin_amdgcn_mfma_f32_16x16x32_f16(aa, bz, mxz, 0,0,0);
      mxr = __builtin_amdgcn_mfma_f32_16x16x32_f16(aa, br, mxr, 0,0,0);
      mxh = __builtin_amdgcn_mfma_f32_16x16x32_f16(aa, bh, mxh, 0,0,0);
      mhz = __builtin_amdgcn_mfma_f32_16x16x32_f16(hh, cz, mhz, 0,0,0);
      mhr = __builtin_amdgcn_mfma_f32_16x16x32_f16(hh, cr, mhr, 0,0,0);
      mhh = __builtin_amdgcn_mfma_f32_16x16x32_f16(hh, ch, mhh, 0,0,0);
    }
    if (kh < 2){
      float b0z = gb[uw],      b0r = gb[64+uw],  b0h = gb[128+uw];
      float b1z = gb[192+uw],  b1r = gb[256+uw], b1h = gb[320+uw];
      #pragma unroll
      for (int r=0;r<4;++r){
        int row = vb + kh*4 + r;
        float z  = sigm(mxz[r] + b0z + mhz[r] + b1z);
        float rr = sigm(mxr[r] + b0r + mhr[r] + b1r);
        float hc = tanhf(mxh[r] + b0h + rr*(mhh[r] + b1h));
        float hold = h_in[(size_t)row*64 + uw];
        h_out[(size_t)row*64 + uw] = z*hold + (1.f - z)*hc;
      }
    }
  }
}

extern "C" void kernel_launch(void* const* d_in, const int* in_sizes, int n_in,
                              void* d_out, int out_size, void* d_ws, size_t ws_size,
                              hipStream_t stream){
  const float* nodef = (const float*)d_in[0];
  const float* edgef = (const float*)d_in[1];
  const int*   pair  = (const int*)  d_in[2];
  const float* ek    = (const float*)d_in[3];
  const float* ebias = (const float*)d_in[4];
  const float* gk    = (const float*)d_in[5];
  const float* rk    = (const float*)d_in[6];
  const float* gb    = (const float*)d_in[7];

  char* ws = (char*)d_ws;
  size_t o = 0;
  auto carve = [&](size_t bytes)->char*{
    char* p = ws + o; o = (o + bytes + 255) & ~255ULL; return p; };
  int*      deg  = (int*)     carve(NN*sizeof(int));
  int*      eidb = (int*)     carve((size_t)NN*SLOT*sizeof(int));
  int2*     enb  = (int2*)    carve((size_t)NN*SLOT*sizeof(int2));
  _Float16* wb   = (_Float16*)carve((size_t)WBN*sizeof(_Float16));
  _Float16* gkt  = (_Float16*)carve((size_t)GTN*sizeof(_Float16));
  _Float16* rkt  = (_Float16*)carve((size_t)GTN*sizeof(_Float16));
  float*    hA   = (float*)   carve((size_t)NN*UU*sizeof(float));
  float*    hB   = (float*)   carve((size_t)NN*UU*sizeof(float));

  build_k <<<(WBN+2*GTN+255)/256, 256, 0, stream>>>(ek, ebias, gk, rk, wb, gkt, rkt, deg);
  bucket_k<<<(NE+255)/256, 256, 0, stream>>>(pair, deg, eidb);
  prep_k  <<<NB, 512, 0, stream>>>(pair, deg, eidb, enb);

  const float* hin = nodef;
  for (int s=0; s<NSTEPS; ++s){
    float* hout = (s == NSTEPS-1) ? (float*)d_out : ((s & 1) ? hB : hA);
    step_k<<<NB, 512, 0, stream>>>(hin, hout, edgef, deg, enb,
                                   wb, gkt, rkt, gb);
    hin = hout;
  }
}